// Round 5
// baseline (2097.293 us; speedup 1.0000x reference)
//
#include <hip/hip_runtime.h>

#define NSRC 50000
#define NDST 50000
#define NE   1600000
#define DD   64
#define NEG  0.2f

// ---------------- workspace layout (bytes) ----------------
#define OFF_FS      ((size_t)0)
#define OFF_FD      (OFF_FS     + (size_t)NSRC*DD*4)          // 12.8 MB
#define OFF_LOGITS  (OFF_FD     + (size_t)NDST*DD*4)          // +12.8 MB
#define OFF_WLA     (OFF_LOGITS + (size_t)NE*4)               // +6.4 MB
#define OFF_CNT     (OFF_WLA    + 512)
#define OFF_CUR     (OFF_CNT    + (size_t)NDST*4 + 256)
#define OFF_ROWOFF  (OFF_CUR    + (size_t)NDST*4 + 256)
#define OFF_BSUM    (OFF_ROWOFF + (size_t)(NDST+1)*4 + 252)
#define OFF_BBASE   (OFF_BSUM   + 1024)
#define OFF_PERM    (OFF_BBASE  + 1024)                        // +6.4 MB  => ~39.7 MB total

// ---------------- K1: node projections + cnt zero + wla precompute ----------------
__global__ __launch_bounds__(256) void k_nodeproj(
    const float* __restrict__ feat_src, const float* __restrict__ feat_dst,
    const float* __restrict__ W_src, const float* __restrict__ b_src,
    const float* __restrict__ W_dst, const float* __restrict__ b_dst,
    const float* __restrict__ W_el, const float* __restrict__ b_el,
    const float* __restrict__ attn,
    float* __restrict__ fs, float* __restrict__ fd,
    float* __restrict__ wla, int* __restrict__ cnt)
{
    int t = threadIdx.x, b = blockIdx.x;
    int gid = b*256 + t;
    if (gid < NDST) cnt[gid] = 0;
    if (b == 0) {
        if (t < DD) {                       // wla[k] = sum_j W_el[k][j]*attn[j]
            float s = 0.f;
            for (int j = 0; j < DD; j++) s += W_el[t*DD+j]*attn[j];
            wla[t] = s;
        } else if (t == DD) {               // bla = b_el . attn
            float s = 0.f;
            for (int j = 0; j < DD; j++) s += b_el[j]*attn[j];
            wla[DD] = s;
        }
    }
    int row = gid;
    if (row >= NSRC + NDST) return;
    int which = (row < NSRC) ? 0 : 1;
    int r = which ? (row - NSRC) : row;
    const float* feat = which ? feat_dst : feat_src;
    const float* bias = which ? b_dst : b_src;
    const float* W    = which ? W_dst : W_src;
    float* outp = which ? (fd + (size_t)r*DD) : (fs + (size_t)r*DD);

    float acc[DD];
#pragma unroll
    for (int j = 0; j < DD; j++) acc[j] = 0.f;

    const float4* frow4 = (const float4*)(feat + (size_t)r*DD);
#pragma unroll
    for (int k4 = 0; k4 < DD/4; k4++) {
        float4 x4 = frow4[k4];
#pragma unroll
        for (int c = 0; c < 4; c++) {
            float xk = (c==0)?x4.x:(c==1)?x4.y:(c==2)?x4.z:x4.w;
            const float4* wr = (const float4*)&W[(k4*4+c)*DD];
#pragma unroll
            for (int jq = 0; jq < DD/4; jq++) {
                float4 w = wr[jq];
                acc[jq*4+0] += xk*w.x; acc[jq*4+1] += xk*w.y;
                acc[jq*4+2] += xk*w.z; acc[jq*4+3] += xk*w.w;
            }
        }
    }
#pragma unroll
    for (int jq = 0; jq < DD/4; jq++) {
        float4 o;
        o.x = acc[jq*4+0] + bias[jq*4+0];
        o.y = acc[jq*4+1] + bias[jq*4+1];
        o.z = acc[jq*4+2] + bias[jq*4+2];
        o.w = acc[jq*4+3] + bias[jq*4+3];
        ((float4*)outp)[jq] = o;
    }
}

// ---------------- K2: histogram of dst ----------------
__global__ void k_hist(const int* __restrict__ dst_idx, int* __restrict__ cnt) {
    int e = blockIdx.x*256 + threadIdx.x;
    if (e < NE) atomicAdd(&cnt[dst_idx[e]], 1);
}

// ---------------- scan (3 phases) ----------------
__global__ __launch_bounds__(1024) void k_scan_a(const int* __restrict__ cnt,
                                                 int* __restrict__ row_off,
                                                 int* __restrict__ bsum) {
    __shared__ int sm[1024];
    int t = threadIdx.x, b = blockIdx.x;
    int i = b*1024 + t;
    int v = (i < NDST) ? cnt[i] : 0;
    sm[t] = v;
    __syncthreads();
    for (int o = 1; o < 1024; o <<= 1) {
        int add = (t >= o) ? sm[t-o] : 0;
        __syncthreads();
        sm[t] += add;
        __syncthreads();
    }
    if (i < NDST) row_off[i+1] = sm[t];
    if (t == 1023) bsum[b] = sm[t];
}

__global__ void k_scan_b(const int* __restrict__ bsum, int* __restrict__ bbase,
                         int* __restrict__ row_off, int nb) {
    if (threadIdx.x == 0 && blockIdx.x == 0) {
        int run = 0;
        for (int b = 0; b < nb; b++) { bbase[b] = run; run += bsum[b]; }
        row_off[0] = 0;
    }
}

__global__ __launch_bounds__(1024) void k_scan_c(const int* __restrict__ cnt,
                                                 const int* __restrict__ bbase,
                                                 int* __restrict__ row_off,
                                                 int* __restrict__ cur) {
    int t = threadIdx.x, b = blockIdx.x;
    int i = b*1024 + t;
    if (i < NDST) {
        int v = row_off[i+1] + bbase[b];
        row_off[i+1] = v;
        cur[i] = v - cnt[i];       // exclusive prefix = bucket start
    }
}

// ---------------- scatter into CSR ----------------
__global__ void k_scatter(const int* __restrict__ dst_idx, int* __restrict__ cur,
                          int* __restrict__ perm) {
    int e = blockIdx.x*256 + threadIdx.x;
    if (e < NE) {
        int p = atomicAdd(&cur[dst_idx[e]], 1);
        perm[p] = e;
    }
}

// ---------------- K_EDGE v3: scalar-pipe W, zero LDS, zero barriers ----------------
// W reads have wave-uniform addresses -> compiler emits s_load (SMEM/K$ path),
// inner loop is v_fmac with one SGPR operand. Activations x[64]/acc[64] in VGPRs.
__global__ __launch_bounds__(256, 3) void k_edge(
    const float* __restrict__ e_feat,
    const float* __restrict__ W_e,  const float* __restrict__ b_e,
    const float* __restrict__ W_m1, const float* __restrict__ b_m1,
    const float* __restrict__ W_m2, const float* __restrict__ b_m2,
    const float* __restrict__ W_m3, const float* __restrict__ b_m3,
    const int* __restrict__ src_idx, const int* __restrict__ dst_idx,
    const float* __restrict__ fs, const float* __restrict__ fd,
    const float* __restrict__ wla,
    float* __restrict__ logits)
{
    int t = threadIdx.x;
    int e = blockIdx.x*256 + t;
    int src = src_idx[e];
    int dst = dst_idx[e];

    // load this edge's e_feat row into registers
    float x[DD];
    {
        const float4* ef4 = (const float4*)(e_feat + (size_t)e*DD);
#pragma unroll
        for (int q = 0; q < DD/4; q++) {
            float4 v = ef4[q];
            x[q*4+0] = v.x; x[q*4+1] = v.y; x[q*4+2] = v.z; x[q*4+3] = v.w;
        }
    }

    float acc[DD];
    // stage loop kept runtime (I$ size); k-loop unrolled (register indexing)
    for (int s = 0; s < 4; s++) {
        const float* Wg = (s==0) ? W_e : (s==1) ? W_m1 : (s==2) ? W_m2 : W_m3;

        if (s > 0) {
#pragma unroll
            for (int j = 0; j < DD; j++) x[j] = fmaxf(x[j], NEG*x[j]);
        }

#pragma unroll
        for (int j = 0; j < DD; j++) acc[j] = 0.f;

#pragma unroll
        for (int k = 0; k < DD; k++) {
            float xk = x[k];
            const float* wr = Wg + k*DD;    // uniform address -> scalar loads
#pragma unroll
            for (int j = 0; j < DD; j++) acc[j] += xk * wr[j];
        }

        if (s == 0) {
            const float4* fsr = (const float4*)(fs + (size_t)src*DD);
#pragma unroll
            for (int jq = 0; jq < DD/4; jq++) {
                float4 v = fsr[jq];
                x[jq*4+0] = acc[jq*4+0] + v.x + b_e[jq*4+0];
                x[jq*4+1] = acc[jq*4+1] + v.y + b_e[jq*4+1];
                x[jq*4+2] = acc[jq*4+2] + v.z + b_e[jq*4+2];
                x[jq*4+3] = acc[jq*4+3] + v.w + b_e[jq*4+3];
            }
        } else if (s == 1) {
#pragma unroll
            for (int j = 0; j < DD; j++) x[j] = acc[j] + b_m1[j];
        } else if (s == 2) {
#pragma unroll
            for (int j = 0; j < DD; j++) x[j] = acc[j] + b_m2[j];
        } else {
            const float4* fdr = (const float4*)(fd + (size_t)dst*DD);
            float lg = wla[DD];   // bla
#pragma unroll
            for (int jq = 0; jq < DD/4; jq++) {
                float4 v = fdr[jq];
#pragma unroll
                for (int c = 0; c < 4; c++) {
                    float vv = (c==0)?v.x:(c==1)?v.y:(c==2)?v.z:v.w;
                    float y = acc[jq*4+c] + b_m3[jq*4+c] + vv;
                    y = fmaxf(y, NEG*y);
                    lg += y * wla[jq*4+c];
                }
            }
            logits[e] = lg;
        }
    }
}

// ---------------- K_AGG v2: chunked two-phase softmax + aggregation ----------------
__global__ __launch_bounds__(256) void k_agg(
    const int* __restrict__ row_off, const int* __restrict__ perm,
    const float* __restrict__ logits, const int* __restrict__ src_idx,
    const float* __restrict__ fs, float* __restrict__ out)
{
    __shared__ float psh[4][64];
    __shared__ int   ssh[4][64];
    int w = threadIdx.x >> 6, lane = threadIdx.x & 63;
    int d = blockIdx.x*4 + w;
    if (d >= NDST) return;
    int off = row_off[d], end = row_off[d+1];
    int deg = end - off;

    // phase 0: max over incoming logits (lane-parallel gather)
    float m = -1e30f;
    for (int i = lane; i < deg; i += 64)
        m = fmaxf(m, logits[perm[off+i]]);
#pragma unroll
    for (int s = 32; s >= 1; s >>= 1)
        m = fmaxf(m, __shfl_xor(m, s, 64));

    // chunked: lanes gather p & src in parallel, then broadcast-accumulate
    float ssum = 0.f, acc = 0.f;
    for (int base = 0; base < deg; base += 64) {
        int i = base + lane;
        float p = 0.f; int sj = 0;
        if (i < deg) {
            int e = perm[off+i];
            p  = __expf(logits[e] - m);
            sj = src_idx[e];
        }
        ssum += p;
        psh[w][lane] = p;
        ssh[w][lane] = sj;
        __builtin_amdgcn_wave_barrier();   // wave-private LDS: order writes before reads
        int n = (deg - base < 64) ? (deg - base) : 64;
        for (int j = 0; j < n; j++) {
            float pj = psh[w][j];
            int   s2 = ssh[w][j];
            acc += pj * fs[(size_t)s2*DD + lane];
        }
        __builtin_amdgcn_wave_barrier();   // reads done before next chunk's writes
    }
#pragma unroll
    for (int s = 32; s >= 1; s >>= 1)
        ssum += __shfl_xor(ssum, s, 64);

    out[(size_t)d*DD + lane] = (deg > 0) ? (acc / ssum) : 0.f;
}

// ---------------- launch ----------------
extern "C" void kernel_launch(void* const* d_in, const int* in_sizes, int n_in,
                              void* d_out, int out_size, void* d_ws, size_t ws_size,
                              hipStream_t stream)
{
    const float* feat_src = (const float*)d_in[0];
    const float* feat_dst = (const float*)d_in[1];
    const float* e_feat   = (const float*)d_in[2];
    const float* W_src = (const float*)d_in[3];
    const float* b_src = (const float*)d_in[4];
    const float* W_dst = (const float*)d_in[5];
    const float* b_dst = (const float*)d_in[6];
    const float* W_e   = (const float*)d_in[7];
    const float* b_e   = (const float*)d_in[8];
    const float* W_m1  = (const float*)d_in[9];
    const float* b_m1  = (const float*)d_in[10];
    const float* W_m2  = (const float*)d_in[11];
    const float* b_m2  = (const float*)d_in[12];
    const float* W_m3  = (const float*)d_in[13];
    const float* b_m3  = (const float*)d_in[14];
    const float* W_el  = (const float*)d_in[15];
    const float* b_el  = (const float*)d_in[16];
    const float* attn  = (const float*)d_in[17];
    const int* src_idx = (const int*)d_in[18];
    const int* dst_idx = (const int*)d_in[19];
    float* out = (float*)d_out;

    char* ws = (char*)d_ws;
    float* fs      = (float*)(ws + OFF_FS);
    float* fd      = (float*)(ws + OFF_FD);
    float* logits  = (float*)(ws + OFF_LOGITS);
    float* wla     = (float*)(ws + OFF_WLA);
    int*   cnt     = (int*)  (ws + OFF_CNT);
    int*   cur     = (int*)  (ws + OFF_CUR);
    int*   row_off = (int*)  (ws + OFF_ROWOFF);
    int*   bsum    = (int*)  (ws + OFF_BSUM);
    int*   bbase   = (int*)  (ws + OFF_BBASE);
    int*   perm    = (int*)  (ws + OFF_PERM);

    const int NB_NODE = (NSRC + NDST + 255) / 256;   // 391
    const int NB_E256 = (NE + 255) / 256;            // 6250
    const int NB_SCAN = (NDST + 1023) / 1024;        // 49

    k_nodeproj<<<NB_NODE, 256, 0, stream>>>(feat_src, feat_dst, W_src, b_src,
                                            W_dst, b_dst, W_el, b_el, attn,
                                            fs, fd, wla, cnt);
    k_hist<<<NB_E256, 256, 0, stream>>>(dst_idx, cnt);
    k_scan_a<<<NB_SCAN, 1024, 0, stream>>>(cnt, row_off, bsum);
    k_scan_b<<<1, 64, 0, stream>>>(bsum, bbase, row_off, NB_SCAN);
    k_scan_c<<<NB_SCAN, 1024, 0, stream>>>(cnt, bbase, row_off, cur);
    k_scatter<<<NB_E256, 256, 0, stream>>>(dst_idx, cur, perm);
    k_edge<<<NE/256, 256, 0, stream>>>(e_feat, W_e, b_e, W_m1, b_m1, W_m2, b_m2,
                                       W_m3, b_m3, src_idx, dst_idx, fs, fd, wla,
                                       logits);
    k_agg<<<(NDST + 3) / 4, 256, 0, stream>>>(row_off, perm, logits, src_idx, fs, out);
}

// Round 8
// 1076.812 us; speedup vs baseline: 1.9477x; 1.9477x over previous
//
#include <hip/hip_runtime.h>

#define NSRC 50000
#define NDST 50000
#define NE   1600000
#define DD   64
#define NEG  0.2f

typedef unsigned short ushort_t;
typedef __attribute__((ext_vector_type(8))) short short8;
typedef __attribute__((ext_vector_type(4))) float f32x4;
#define MFMA __builtin_amdgcn_mfma_f32_16x16x32_bf16

// ---------------- workspace layout (bytes) ----------------
#define OFF_FS      ((size_t)0)
#define OFF_FD      (OFF_FS     + (size_t)NSRC*DD*4)          // 12.8 MB
#define OFF_LOGITS  (OFF_FD     + (size_t)NDST*DD*4)          // +12.8 MB
#define OFF_WLA     (OFF_LOGITS + (size_t)NE*4)               // +6.4 MB
#define OFF_CNT     (OFF_WLA    + 512)
#define OFF_CUR     (OFF_CNT    + (size_t)NDST*4 + 256)
#define OFF_ROWOFF  (OFF_CUR    + (size_t)NDST*4 + 256)
#define OFF_BSUM    (OFF_ROWOFF + (size_t)(NDST+1)*4 + 252)
#define OFF_BBASE   (OFF_BSUM   + 1024)
#define OFF_PERM    (OFF_BBASE  + 1024)                        // +6.4 MB
#define OFF_WT      ((OFF_PERM + (size_t)NE*4 + 255) & ~(size_t)255)  // 6 x 16KB packed W

// split fp32 -> bf16 hi (RNE) + bf16 lo (trunc of exact remainder)
__device__ __forceinline__ void bsplit(float x, ushort_t& h, ushort_t& l) {
    unsigned u = __float_as_uint(x);
    unsigned hr = u + 0x7fffu + ((u >> 16) & 1u);   // round-nearest-even to bf16
    h = (ushort_t)(hr >> 16);
    float hf = __uint_as_float(((unsigned)h) << 16);
    float lf = x - hf;                               // exact
    l = (ushort_t)(__float_as_uint(lf) >> 16);       // trunc
}

// ---------------- K_PREP: W->bf16x2 planes, wla, cnt zero ----------------
// wt layout: mat 0..5 = {W_e,W_m1,W_m2,W_m3,W_src,W_dst}; per mat: hi[n*64+k] (4096), lo[n*64+k] (4096)
__global__ __launch_bounds__(256) void k_prep(
    const float* __restrict__ We, const float* __restrict__ Wm1,
    const float* __restrict__ Wm2, const float* __restrict__ Wm3,
    const float* __restrict__ Wsrc, const float* __restrict__ Wdst,
    const float* __restrict__ Wel, const float* __restrict__ bel,
    const float* __restrict__ attn,
    ushort_t* __restrict__ wt, float* __restrict__ wla, int* __restrict__ cnt)
{
    int b = blockIdx.x, t = threadIdx.x;
    if (b < 6) {
        const float* W = (b==0)?We:(b==1)?Wm1:(b==2)?Wm2:(b==3)?Wm3:(b==4)?Wsrc:Wdst;
        ushort_t* hi = wt + (size_t)b*8192;
        ushort_t* lo = hi + 4096;
        for (int j = t; j < 4096; j += 256) {
            int n = j >> 6, k = j & 63;
            ushort_t h, l; bsplit(W[k*64 + n], h, l);   // store transposed: [n][k]
            hi[j] = h; lo[j] = l;
        }
    } else if (b == 6) {
        if (t < DD) { float s = 0.f; for (int j = 0; j < DD; j++) s += Wel[t*DD+j]*attn[j]; wla[t] = s; }
        else if (t == DD) { float s = 0.f; for (int j = 0; j < DD; j++) s += bel[j]*attn[j]; wla[DD] = s; }
    } else {
        int gid = (b-7)*256 + t;
        if (gid < NDST) cnt[gid] = 0;
    }
}

// ---------------- K_NODEPROJ (MFMA): fs/fd = feat @ W + b ----------------
__global__ __launch_bounds__(256, 3) void k_nodeproj(
    const float* __restrict__ feat_src, const float* __restrict__ feat_dst,
    const float* __restrict__ b_src, const float* __restrict__ b_dst,
    const ushort_t* __restrict__ wt,
    float* __restrict__ fs, float* __restrict__ fd)
{
    __shared__ ushort_t Xhi[64][72], Xlo[64][72], Whi[64][72], Wlo[64][72];
    __shared__ float bshs[64];
    int t = threadIdx.x, b = blockIdx.x;
    int which = (b >= 782);
    int rbase = (which ? b - 782 : b) * 64;
    const float* feat = which ? feat_dst : feat_src;
    const float* bias = which ? b_dst : b_src;
    float* outp = which ? fd : fs;
    const ushort_t* g = wt + (size_t)(4 + which) * 8192;

    if (t < 64) bshs[t] = bias[t];
    {   // stage feat tile -> bf16x2 planes
        int row = t >> 2, cs = (t & 3) * 16;
        int grow = rbase + row;
        const float4* src = (const float4*)(feat + (size_t)grow*DD + cs);
#pragma unroll
        for (int q = 0; q < 4; q++) {
            float4 v = (grow < NSRC) ? src[q] : make_float4(0.f,0.f,0.f,0.f);
#pragma unroll
            for (int j = 0; j < 4; j++) {
                float x = (j==0)?v.x:(j==1)?v.y:(j==2)?v.z:v.w;
                ushort_t h, l; bsplit(x, h, l);
                Xhi[row][cs+q*4+j] = h; Xlo[row][cs+q*4+j] = l;
            }
        }
    }
    {   // stage W planes: 16 shorts (= 2 x uint4) per thread  [R7 fix: was 8]
        int n = t >> 2, ks = (t & 3) * 16;
        *(uint4*)&Whi[n][ks]   = *(const uint4*)&g[n*64 + ks];
        *(uint4*)&Whi[n][ks+8] = *(const uint4*)&g[n*64 + ks + 8];
        *(uint4*)&Wlo[n][ks]   = *(const uint4*)&g[4096 + n*64 + ks];
        *(uint4*)&Wlo[n][ks+8] = *(const uint4*)&g[4096 + n*64 + ks + 8];
    }
    __syncthreads();

    int wv = t >> 6, lane = t & 63;
    int mrow = 16*wv + (lane & 15);
    int abase = (lane >> 4) * 8;
    short8 ah0 = *(const short8*)&Xhi[mrow][abase];
    short8 ah1 = *(const short8*)&Xhi[mrow][32 + abase];
    short8 al0 = *(const short8*)&Xlo[mrow][abase];
    short8 al1 = *(const short8*)&Xlo[mrow][32 + abase];
#pragma unroll
    for (int tt = 0; tt < 4; tt++) {
        int n = (lane & 15) + 16*tt;
        short8 bh0 = *(const short8*)&Whi[n][abase];
        short8 bh1 = *(const short8*)&Whi[n][32 + abase];
        short8 bl0 = *(const short8*)&Wlo[n][abase];
        short8 bl1 = *(const short8*)&Wlo[n][32 + abase];
        f32x4 c = {0.f, 0.f, 0.f, 0.f};
        c = MFMA(ah0, bh0, c, 0,0,0); c = MFMA(ah1, bh1, c, 0,0,0);
        c = MFMA(ah0, bl0, c, 0,0,0); c = MFMA(ah1, bl1, c, 0,0,0);
        c = MFMA(al0, bh0, c, 0,0,0); c = MFMA(al1, bh1, c, 0,0,0);
#pragma unroll
        for (int r = 0; r < 4; r++) {
            int m = 16*wv + (lane >> 4)*4 + r;
            int grow = rbase + m;
            if (grow < NSRC) outp[(size_t)grow*DD + n] = c[r] + bshs[n];
        }
    }
}

// ---------------- K2: histogram of dst ----------------
__global__ void k_hist(const int* __restrict__ dst_idx, int* __restrict__ cnt) {
    int e = blockIdx.x*256 + threadIdx.x;
    if (e < NE) atomicAdd(&cnt[dst_idx[e]], 1);
}

// ---------------- scan (3 phases) ----------------
__global__ __launch_bounds__(1024) void k_scan_a(const int* __restrict__ cnt,
                                                 int* __restrict__ row_off,
                                                 int* __restrict__ bsum) {
    __shared__ int sm[1024];
    int t = threadIdx.x, b = blockIdx.x;
    int i = b*1024 + t;
    int v = (i < NDST) ? cnt[i] : 0;
    sm[t] = v;
    __syncthreads();
    for (int o = 1; o < 1024; o <<= 1) {
        int add = (t >= o) ? sm[t-o] : 0;
        __syncthreads();
        sm[t] += add;
        __syncthreads();
    }
    if (i < NDST) row_off[i+1] = sm[t];
    if (t == 1023) bsum[b] = sm[t];
}

__global__ void k_scan_b(const int* __restrict__ bsum, int* __restrict__ bbase,
                         int* __restrict__ row_off, int nb) {
    if (threadIdx.x == 0 && blockIdx.x == 0) {
        int run = 0;
        for (int b = 0; b < nb; b++) { bbase[b] = run; run += bsum[b]; }
        row_off[0] = 0;
    }
}

__global__ __launch_bounds__(1024) void k_scan_c(const int* __restrict__ cnt,
                                                 const int* __restrict__ bbase,
                                                 int* __restrict__ row_off,
                                                 int* __restrict__ cur) {
    int t = threadIdx.x, b = blockIdx.x;
    int i = b*1024 + t;
    if (i < NDST) {
        int v = row_off[i+1] + bbase[b];
        row_off[i+1] = v;
        cur[i] = v - cnt[i];
    }
}

// ---------------- scatter into CSR ----------------
__global__ void k_scatter(const int* __restrict__ dst_idx, int* __restrict__ cur,
                          int* __restrict__ perm) {
    int e = blockIdx.x*256 + threadIdx.x;
    if (e < NE) {
        int p = atomicAdd(&cur[dst_idx[e]], 1);
        perm[p] = e;
    }
}

// ---------------- K_EDGE v4: bf16x2-split MFMA, 64 edges/block ----------------
// X planes (wave-private rows) hold stage input; W planes reloaded per stage.
__global__ __launch_bounds__(256, 3) void k_edge(
    const float* __restrict__ e_feat, const ushort_t* __restrict__ wt,
    const float* __restrict__ b_e,  const float* __restrict__ b_m1,
    const float* __restrict__ b_m2, const float* __restrict__ b_m3,
    const int* __restrict__ src_idx, const int* __restrict__ dst_idx,
    const float* __restrict__ fs, const float* __restrict__ fd,
    const float* __restrict__ wla,
    float* __restrict__ logits)
{
    __shared__ ushort_t Xhi[64][72], Xlo[64][72], Whi[64][72], Wlo[64][72];
    __shared__ float bshs[5*64 + 2];

    int t = threadIdx.x;
    int ebase = blockIdx.x * 64;
    int wv = t >> 6, lane = t & 63;

    if (t < 64) {
        bshs[t]       = b_e[t];
        bshs[64+t]    = b_m1[t];
        bshs[128+t]   = b_m2[t];
        bshs[192+t]   = b_m3[t];
        bshs[256+t]   = wla[t];
    }
    if (t == 64) bshs[320] = wla[DD];

    {   // stage e_feat tile -> bf16x2 planes (coalesced float4 reads)
        int row = t >> 2, cs = (t & 3) * 16;
        const float4* src = (const float4*)(e_feat + (size_t)(ebase + row)*DD + cs);
#pragma unroll
        for (int q = 0; q < 4; q++) {
            float4 v = src[q];
#pragma unroll
            for (int j = 0; j < 4; j++) {
                float x = (j==0)?v.x:(j==1)?v.y:(j==2)?v.z:v.w;
                ushort_t h, l; bsplit(x, h, l);
                Xhi[row][cs+q*4+j] = h; Xlo[row][cs+q*4+j] = l;
            }
        }
    }

    // this wave's edge ids for epilogue gathers (uniform across 16-lane groups)
    int se[4], de[4];
#pragma unroll
    for (int r = 0; r < 4; r++) {
        int eidx = ebase + 16*wv + ((lane >> 4) << 2) + r;
        se[r] = src_idx[eidx];
        de[r] = dst_idx[eidx];
    }

    int mrow = 16*wv + (lane & 15);
    int abase = (lane >> 4) * 8;

#pragma unroll
    for (int s = 0; s < 4; s++) {
        __syncthreads();   // prior stage W reads + X writes complete
        {   // load stage-s W planes: 16 shorts (= 2 x uint4) per thread  [R7 fix: was 8]
            const ushort_t* g = wt + (size_t)s * 8192;
            int n = t >> 2, ks = (t & 3) * 16;
            *(uint4*)&Whi[n][ks]   = *(const uint4*)&g[n*64 + ks];
            *(uint4*)&Whi[n][ks+8] = *(const uint4*)&g[n*64 + ks + 8];
            *(uint4*)&Wlo[n][ks]   = *(const uint4*)&g[4096 + n*64 + ks];
            *(uint4*)&Wlo[n][ks+8] = *(const uint4*)&g[4096 + n*64 + ks + 8];
        }
        __syncthreads();

        short8 ah0 = *(const short8*)&Xhi[mrow][abase];
        short8 ah1 = *(const short8*)&Xhi[mrow][32 + abase];
        short8 al0 = *(const short8*)&Xlo[mrow][abase];
        short8 al1 = *(const short8*)&Xlo[mrow][32 + abase];

        float lg[4] = {0.f, 0.f, 0.f, 0.f};
#pragma unroll
        for (int tt = 0; tt < 4; tt++) {
            int n = (lane & 15) + 16*tt;
            short8 bh0 = *(const short8*)&Whi[n][abase];
            short8 bh1 = *(const short8*)&Whi[n][32 + abase];
            short8 bl0 = *(const short8*)&Wlo[n][abase];
            short8 bl1 = *(const short8*)&Wlo[n][32 + abase];
            f32x4 c = {0.f, 0.f, 0.f, 0.f};
            c = MFMA(ah0, bh0, c, 0,0,0); c = MFMA(ah1, bh1, c, 0,0,0);
            c = MFMA(ah0, bl0, c, 0,0,0); c = MFMA(ah1, bl1, c, 0,0,0);
            c = MFMA(al0, bh0, c, 0,0,0); c = MFMA(al1, bh1, c, 0,0,0);
#pragma unroll
            for (int r = 0; r < 4; r++) {
                int m = 16*wv + (lane >> 4)*4 + r;
                float val = c[r];
                if (s == 0)      val += bshs[n]     + fs[(size_t)se[r]*DD + n];
                else if (s == 1) val += bshs[64+n];
                else if (s == 2) val += bshs[128+n];
                else             val += bshs[192+n] + fd[(size_t)de[r]*DD + n];
                if (s < 3) {
                    float xn = fmaxf(val, NEG*val);     // lrelu -> next stage input
                    ushort_t h, l; bsplit(xn, h, l);
                    Xhi[m][n] = h; Xlo[m][n] = l;
                } else {
                    float y = fmaxf(val, NEG*val);
                    lg[r] += y * bshs[256+n];
                }
            }
        }
        if (s == 3) {
#pragma unroll
            for (int r = 0; r < 4; r++) {
#pragma unroll
                for (int off = 1; off < 16; off <<= 1)
                    lg[r] += __shfl_xor(lg[r], off, 64);
                if ((lane & 15) == 0)
                    logits[ebase + 16*wv + (lane >> 4)*4 + r] = lg[r] + bshs[320];
            }
        }
    }
}

// ---------------- K_AGG: chunked two-phase softmax + aggregation ----------------
__global__ __launch_bounds__(256) void k_agg(
    const int* __restrict__ row_off, const int* __restrict__ perm,
    const float* __restrict__ logits, const int* __restrict__ src_idx,
    const float* __restrict__ fs, float* __restrict__ out)
{
    __shared__ float psh[4][64];
    __shared__ int   ssh[4][64];
    int w = threadIdx.x >> 6, lane = threadIdx.x & 63;
    int d = blockIdx.x*4 + w;
    if (d >= NDST) return;
    int off = row_off[d], end = row_off[d+1];
    int deg = end - off;

    float m = -1e30f;
    for (int i = lane; i < deg; i += 64)
        m = fmaxf(m, logits[perm[off+i]]);
#pragma unroll
    for (int s = 32; s >= 1; s >>= 1)
        m = fmaxf(m, __shfl_xor(m, s, 64));

    float ssum = 0.f, acc = 0.f;
    for (int base = 0; base < deg; base += 64) {
        int i = base + lane;
        float p = 0.f; int sj = 0;
        if (i < deg) {
            int e = perm[off+i];
            p  = __expf(logits[e] - m);
            sj = src_idx[e];
        }
        ssum += p;
        psh[w][lane] = p;
        ssh[w][lane] = sj;
        __builtin_amdgcn_wave_barrier();
        int n = (deg - base < 64) ? (deg - base) : 64;
        for (int j = 0; j < n; j++) {
            float pj = psh[w][j];
            int   s2 = ssh[w][j];
            acc += pj * fs[(size_t)s2*DD + lane];
        }
        __builtin_amdgcn_wave_barrier();
    }
#pragma unroll
    for (int s = 32; s >= 1; s >>= 1)
        ssum += __shfl_xor(ssum, s, 64);

    out[(size_t)d*DD + lane] = (deg > 0) ? (acc / ssum) : 0.f;
}

// ---------------- launch ----------------
extern "C" void kernel_launch(void* const* d_in, const int* in_sizes, int n_in,
                              void* d_out, int out_size, void* d_ws, size_t ws_size,
                              hipStream_t stream)
{
    const float* feat_src = (const float*)d_in[0];
    const float* feat_dst = (const float*)d_in[1];
    const float* e_feat   = (const float*)d_in[2];
    const float* W_src = (const float*)d_in[3];
    const float* b_src = (const float*)d_in[4];
    const float* W_dst = (const float*)d_in[5];
    const float* b_dst = (const float*)d_in[6];
    const float* W_e   = (const float*)d_in[7];
    const float* b_e   = (const float*)d_in[8];
    const float* W_m1  = (const float*)d_in[9];
    const float* b_m1  = (const float*)d_in[10];
    const float* W_m2  = (const float*)d_in[11];
    const float* b_m2  = (const float*)d_in[12];
    const float* W_m3  = (const float*)d_in[13];
    const float* b_m3  = (const float*)d_in[14];
    const float* W_el  = (const float*)d_in[15];
    const float* b_el  = (const float*)d_in[16];
    const float* attn  = (const float*)d_in[17];
    const int* src_idx = (const int*)d_in[18];
    const int* dst_idx = (const int*)d_in[19];
    float* out = (float*)d_out;

    char* ws = (char*)d_ws;
    float* fs      = (float*)(ws + OFF_FS);
    float* fd      = (float*)(ws + OFF_FD);
    float* logits  = (float*)(ws + OFF_LOGITS);
    float* wla     = (float*)(ws + OFF_WLA);
    int*   cnt     = (int*)  (ws + OFF_CNT);
    int*   cur     = (int*)  (ws + OFF_CUR);
    int*   row_off = (int*)  (ws + OFF_ROWOFF);
    int*   bsum    = (int*)  (ws + OFF_BSUM);
    int*   bbase   = (int*)  (ws + OFF_BBASE);
    int*   perm    = (int*)  (ws + OFF_PERM);
    ushort_t* wt   = (ushort_t*)(ws + OFF_WT);

    const int NB_E256 = (NE + 255) / 256;            // 6250
    const int NB_SCAN = (NDST + 1023) / 1024;        // 49
    const int NB_PREP = 7 + (NDST + 255) / 256;      // 7 + 196

    k_prep<<<NB_PREP, 256, 0, stream>>>(W_e, W_m1, W_m2, W_m3, W_src, W_dst,
                                        W_el, b_el, attn, wt, wla, cnt);
    k_nodeproj<<<1564, 256, 0, stream>>>(feat_src, feat_dst, b_src, b_dst, wt, fs, fd);
    k_hist<<<NB_E256, 256, 0, stream>>>(dst_idx, cnt);
    k_scan_a<<<NB_SCAN, 1024, 0, stream>>>(cnt, row_off, bsum);
    k_scan_b<<<1, 64, 0, stream>>>(bsum, bbase, row_off, NB_SCAN);
    k_scan_c<<<NB_SCAN, 1024, 0, stream>>>(cnt, bbase, row_off, cur);
    k_scatter<<<NB_E256, 256, 0, stream>>>(dst_idx, cur, perm);
    k_edge<<<NE/64, 256, 0, stream>>>(e_feat, wt, b_e, b_m1, b_m2, b_m3,
                                      src_idx, dst_idx, fs, fd, wla, logits);
    k_agg<<<(NDST + 3) / 4, 256, 0, stream>>>(row_off, perm, logits, src_idx, fs, out);
}

// Round 9
// 1029.646 us; speedup vs baseline: 2.0369x; 1.0458x over previous
//
#include <hip/hip_runtime.h>

#define NSRC 50000
#define NDST 50000
#define NE   1600000
#define DD   64
#define NEG  0.2f

typedef unsigned short ushort_t;
typedef __attribute__((ext_vector_type(8))) short short8;
typedef __attribute__((ext_vector_type(4))) float f32x4;
#define MFMA __builtin_amdgcn_mfma_f32_16x16x32_bf16

// ---------------- workspace layout (bytes) ----------------
#define OFF_FS      ((size_t)0)
#define OFF_FD      (OFF_FS     + (size_t)NSRC*DD*4)          // 12.8 MB
#define OFF_LOGITS  (OFF_FD     + (size_t)NDST*DD*4)          // +12.8 MB
#define OFF_WLA     (OFF_LOGITS + (size_t)NE*4)               // +6.4 MB
#define OFF_CNT     (OFF_WLA    + 512)
#define OFF_CUR     (OFF_CNT    + (size_t)NDST*4 + 256)
#define OFF_ROWOFF  (OFF_CUR    + (size_t)NDST*4 + 256)
#define OFF_BSUM    (OFF_ROWOFF + (size_t)(NDST+1)*4 + 252)
#define OFF_BBASE   (OFF_BSUM   + 1024)
#define OFF_PERM    (OFF_BBASE  + 1024)                        // +6.4 MB
#define OFF_WT      ((OFF_PERM + (size_t)NE*4 + 255) & ~(size_t)255)  // 6 x 16KB packed W

__device__ __forceinline__ ushort_t rne16(float x) {           // fp32 -> bf16 RNE
    unsigned u = __float_as_uint(x);
    return (ushort_t)((u + 0x7fffu + ((u >> 16) & 1u)) >> 16);
}

// split fp32 -> bf16 hi (RNE) + bf16 lo (trunc of exact remainder)
__device__ __forceinline__ void bsplit(float x, ushort_t& h, ushort_t& l) {
    h = rne16(x);
    float hf = __uint_as_float(((unsigned)h) << 16);
    float lf = x - hf;                               // exact
    l = (ushort_t)(__float_as_uint(lf) >> 16);       // trunc
}

// ---------------- K_PREP: W->bf16x2 planes, wla, cnt zero ----------------
// wt layout: mat 0..5 = {W_e,W_m1,W_m2,W_m3,W_src,W_dst}; per mat: hi[n*64+k] (4096), lo[n*64+k] (4096)
__global__ __launch_bounds__(256) void k_prep(
    const float* __restrict__ We, const float* __restrict__ Wm1,
    const float* __restrict__ Wm2, const float* __restrict__ Wm3,
    const float* __restrict__ Wsrc, const float* __restrict__ Wdst,
    const float* __restrict__ Wel, const float* __restrict__ bel,
    const float* __restrict__ attn,
    ushort_t* __restrict__ wt, float* __restrict__ wla, int* __restrict__ cnt)
{
    int b = blockIdx.x, t = threadIdx.x;
    if (b < 6) {
        const float* W = (b==0)?We:(b==1)?Wm1:(b==2)?Wm2:(b==3)?Wm3:(b==4)?Wsrc:Wdst;
        ushort_t* hi = wt + (size_t)b*8192;
        ushort_t* lo = hi + 4096;
        for (int j = t; j < 4096; j += 256) {
            int n = j >> 6, k = j & 63;
            ushort_t h, l; bsplit(W[k*64 + n], h, l);   // store transposed: [n][k]
            hi[j] = h; lo[j] = l;
        }
    } else if (b == 6) {
        if (t < DD) { float s = 0.f; for (int j = 0; j < DD; j++) s += Wel[t*DD+j]*attn[j]; wla[t] = s; }
        else if (t == DD) { float s = 0.f; for (int j = 0; j < DD; j++) s += bel[j]*attn[j]; wla[DD] = s; }
    } else {
        int gid = (b-7)*256 + t;
        if (gid < NDST) cnt[gid] = 0;
    }
}

// ---------------- K_NODEPROJ (MFMA, dual-plane X and W): fs/fd = feat @ W + b ----------------
__global__ __launch_bounds__(256, 3) void k_nodeproj(
    const float* __restrict__ feat_src, const float* __restrict__ feat_dst,
    const float* __restrict__ b_src, const float* __restrict__ b_dst,
    const ushort_t* __restrict__ wt,
    float* __restrict__ fs, float* __restrict__ fd)
{
    __shared__ ushort_t Xhi[64][72], Xlo[64][72], Whi[64][72], Wlo[64][72];
    __shared__ float bshs[64];
    int t = threadIdx.x, b = blockIdx.x;
    int which = (b >= 782);
    int rbase = (which ? b - 782 : b) * 64;
    const float* feat = which ? feat_dst : feat_src;
    const float* bias = which ? b_dst : b_src;
    float* outp = which ? fd : fs;
    const ushort_t* g = wt + (size_t)(4 + which) * 8192;

    if (t < 64) bshs[t] = bias[t];
    {   // stage feat tile -> bf16x2 planes
        int row = t >> 2, cs = (t & 3) * 16;
        int grow = rbase + row;
        const float4* src = (const float4*)(feat + (size_t)grow*DD + cs);
#pragma unroll
        for (int q = 0; q < 4; q++) {
            float4 v = (grow < NSRC) ? src[q] : make_float4(0.f,0.f,0.f,0.f);
#pragma unroll
            for (int j = 0; j < 4; j++) {
                float x = (j==0)?v.x:(j==1)?v.y:(j==2)?v.z:v.w;
                ushort_t h, l; bsplit(x, h, l);
                Xhi[row][cs+q*4+j] = h; Xlo[row][cs+q*4+j] = l;
            }
        }
    }
    {   // stage W planes: 16 shorts (= 2 x uint4) per thread
        int n = t >> 2, ks = (t & 3) * 16;
        *(uint4*)&Whi[n][ks]   = *(const uint4*)&g[n*64 + ks];
        *(uint4*)&Whi[n][ks+8] = *(const uint4*)&g[n*64 + ks + 8];
        *(uint4*)&Wlo[n][ks]   = *(const uint4*)&g[4096 + n*64 + ks];
        *(uint4*)&Wlo[n][ks+8] = *(const uint4*)&g[4096 + n*64 + ks + 8];
    }
    __syncthreads();

    int wv = t >> 6, lane = t & 63;
    int mrow = 16*wv + (lane & 15);
    int abase = (lane >> 4) * 8;
    short8 ah0 = *(const short8*)&Xhi[mrow][abase];
    short8 ah1 = *(const short8*)&Xhi[mrow][32 + abase];
    short8 al0 = *(const short8*)&Xlo[mrow][abase];
    short8 al1 = *(const short8*)&Xlo[mrow][32 + abase];
#pragma unroll
    for (int tt = 0; tt < 4; tt++) {
        int n = (lane & 15) + 16*tt;
        short8 bh0 = *(const short8*)&Whi[n][abase];
        short8 bh1 = *(const short8*)&Whi[n][32 + abase];
        short8 bl0 = *(const short8*)&Wlo[n][abase];
        short8 bl1 = *(const short8*)&Wlo[n][32 + abase];
        f32x4 c = {0.f, 0.f, 0.f, 0.f};
        c = MFMA(ah0, bh0, c, 0,0,0); c = MFMA(ah1, bh1, c, 0,0,0);
        c = MFMA(ah0, bl0, c, 0,0,0); c = MFMA(ah1, bl1, c, 0,0,0);
        c = MFMA(al0, bh0, c, 0,0,0); c = MFMA(al1, bh1, c, 0,0,0);
#pragma unroll
        for (int r = 0; r < 4; r++) {
            int m = 16*wv + (lane >> 4)*4 + r;
            int grow = rbase + m;
            if (grow < NSRC) outp[(size_t)grow*DD + n] = c[r] + bshs[n];
        }
    }
}

// ---------------- K2: histogram of dst ----------------
__global__ void k_hist(const int* __restrict__ dst_idx, int* __restrict__ cnt) {
    int e = blockIdx.x*256 + threadIdx.x;
    if (e < NE) atomicAdd(&cnt[dst_idx[e]], 1);
}

// ---------------- scan (3 phases) ----------------
__global__ __launch_bounds__(1024) void k_scan_a(const int* __restrict__ cnt,
                                                 int* __restrict__ row_off,
                                                 int* __restrict__ bsum) {
    __shared__ int sm[1024];
    int t = threadIdx.x, b = blockIdx.x;
    int i = b*1024 + t;
    int v = (i < NDST) ? cnt[i] : 0;
    sm[t] = v;
    __syncthreads();
    for (int o = 1; o < 1024; o <<= 1) {
        int add = (t >= o) ? sm[t-o] : 0;
        __syncthreads();
        sm[t] += add;
        __syncthreads();
    }
    if (i < NDST) row_off[i+1] = sm[t];
    if (t == 1023) bsum[b] = sm[t];
}

__global__ void k_scan_b(const int* __restrict__ bsum, int* __restrict__ bbase,
                         int* __restrict__ row_off, int nb) {
    if (threadIdx.x == 0 && blockIdx.x == 0) {
        int run = 0;
        for (int b = 0; b < nb; b++) { bbase[b] = run; run += bsum[b]; }
        row_off[0] = 0;
    }
}

__global__ __launch_bounds__(1024) void k_scan_c(const int* __restrict__ cnt,
                                                 const int* __restrict__ bbase,
                                                 int* __restrict__ row_off,
                                                 int* __restrict__ cur) {
    int t = threadIdx.x, b = blockIdx.x;
    int i = b*1024 + t;
    if (i < NDST) {
        int v = row_off[i+1] + bbase[b];
        row_off[i+1] = v;
        cur[i] = v - cnt[i];
    }
}

// ---------------- scatter into CSR ----------------
__global__ void k_scatter(const int* __restrict__ dst_idx, int* __restrict__ cur,
                          int* __restrict__ perm) {
    int e = blockIdx.x*256 + threadIdx.x;
    if (e < NE) {
        int p = atomicAdd(&cur[dst_idx[e]], 1);
        perm[p] = e;
    }
}

// ---------------- K_EDGE v5: X hi-only (bf16), W dual-plane, direct stage-0 A ----------------
// Error = X-quantization only (W split is exact): ~2^-9 rel per stage.
__global__ __launch_bounds__(256, 4) void k_edge(
    const float* __restrict__ e_feat, const ushort_t* __restrict__ wt,
    const float* __restrict__ b_e,  const float* __restrict__ b_m1,
    const float* __restrict__ b_m2, const float* __restrict__ b_m3,
    const int* __restrict__ src_idx, const int* __restrict__ dst_idx,
    const float* __restrict__ fs, const float* __restrict__ fd,
    const float* __restrict__ wla,
    float* __restrict__ logits)
{
    __shared__ ushort_t Xhi[64][72], Whi[64][72], Wlo[64][72];
    __shared__ float bshs[5*64 + 2];

    int t = threadIdx.x;
    int ebase = blockIdx.x * 64;
    int wv = t >> 6, lane = t & 63;
    int g = lane >> 4;
    int mrow = 16*wv + (lane & 15);
    int abase = g * 8;

    if (t < 64) {
        bshs[t]       = b_e[t];
        bshs[64+t]    = b_m1[t];
        bshs[128+t]   = b_m2[t];
        bshs[192+t]   = b_m3[t];
        bshs[256+t]   = wla[t];
    }
    if (t == 64) bshs[320] = wla[DD];

    // this wave's edge ids for epilogue gathers
    int se[4], de[4];
#pragma unroll
    for (int r = 0; r < 4; r++) {
        int eidx = ebase + 16*wv + g*4 + r;
        se[r] = src_idx[eidx];
        de[r] = dst_idx[eidx];
    }

    // stage-0 A-fragments straight from global (e_feat rows are A-frag shaped)
    short8 ah0, ah1;
    {
        const float* ef = e_feat + (size_t)(ebase + mrow)*DD;
        float4 u0 = *(const float4*)(ef + abase);
        float4 u1 = *(const float4*)(ef + abase + 4);
        float4 u2 = *(const float4*)(ef + 32 + abase);
        float4 u3 = *(const float4*)(ef + 32 + abase + 4);
        ah0[0]=(short)rne16(u0.x); ah0[1]=(short)rne16(u0.y); ah0[2]=(short)rne16(u0.z); ah0[3]=(short)rne16(u0.w);
        ah0[4]=(short)rne16(u1.x); ah0[5]=(short)rne16(u1.y); ah0[6]=(short)rne16(u1.z); ah0[7]=(short)rne16(u1.w);
        ah1[0]=(short)rne16(u2.x); ah1[1]=(short)rne16(u2.y); ah1[2]=(short)rne16(u2.z); ah1[3]=(short)rne16(u2.w);
        ah1[4]=(short)rne16(u3.x); ah1[5]=(short)rne16(u3.y); ah1[6]=(short)rne16(u3.z); ah1[7]=(short)rne16(u3.w);
    }

    float lg[4] = {0.f, 0.f, 0.f, 0.f};

#pragma unroll
    for (int s = 0; s < 4; s++) {
        __syncthreads();   // prior stage W/X reads complete
        {   // stage W dual planes (16KB) from prepped global (L2-resident)
            const ushort_t* wg = wt + (size_t)s * 8192;
            int n = t >> 2, ks = (t & 3) * 16;
            *(uint4*)&Whi[n][ks]   = *(const uint4*)&wg[n*64 + ks];
            *(uint4*)&Whi[n][ks+8] = *(const uint4*)&wg[n*64 + ks + 8];
            *(uint4*)&Wlo[n][ks]   = *(const uint4*)&wg[4096 + n*64 + ks];
            *(uint4*)&Wlo[n][ks+8] = *(const uint4*)&wg[4096 + n*64 + ks + 8];
        }
        __syncthreads();

        if (s > 0) {   // A-frags from LDS (written by this wave's previous epilogue)
            ah0 = *(const short8*)&Xhi[mrow][abase];
            ah1 = *(const short8*)&Xhi[mrow][32 + abase];
        }

#pragma unroll
        for (int tt = 0; tt < 4; tt++) {
            int n = (lane & 15) + 16*tt;
            short8 bh0 = *(const short8*)&Whi[n][abase];
            short8 bh1 = *(const short8*)&Whi[n][32 + abase];
            short8 bl0 = *(const short8*)&Wlo[n][abase];
            short8 bl1 = *(const short8*)&Wlo[n][32 + abase];
            f32x4 c = {0.f, 0.f, 0.f, 0.f};
            c = MFMA(ah0, bh0, c, 0,0,0); c = MFMA(ah1, bh1, c, 0,0,0);
            c = MFMA(ah0, bl0, c, 0,0,0); c = MFMA(ah1, bl1, c, 0,0,0);
#pragma unroll
            for (int r = 0; r < 4; r++) {
                int m = 16*wv + g*4 + r;
                float val = c[r];
                if (s == 0)      val += bshs[n]     + fs[(size_t)se[r]*DD + n];
                else if (s == 1) val += bshs[64+n];
                else if (s == 2) val += bshs[128+n];
                else             val += bshs[192+n] + fd[(size_t)de[r]*DD + n];
                if (s < 3) {
                    float xn = fmaxf(val, NEG*val);     // lrelu -> next stage input
                    Xhi[m][n] = rne16(xn);
                } else {
                    float y = fmaxf(val, NEG*val);
                    lg[r] += y * bshs[256+n];
                }
            }
        }
    }

#pragma unroll
    for (int r = 0; r < 4; r++) {
#pragma unroll
        for (int off = 1; off < 16; off <<= 1)
            lg[r] += __shfl_xor(lg[r], off, 64);
        if ((lane & 15) == 0)
            logits[ebase + 16*wv + g*4 + r] = lg[r] + bshs[320];
    }
}

// ---------------- K_AGG: chunked two-phase softmax + aggregation ----------------
__global__ __launch_bounds__(256) void k_agg(
    const int* __restrict__ row_off, const int* __restrict__ perm,
    const float* __restrict__ logits, const int* __restrict__ src_idx,
    const float* __restrict__ fs, float* __restrict__ out)
{
    __shared__ float psh[4][64];
    __shared__ int   ssh[4][64];
    int w = threadIdx.x >> 6, lane = threadIdx.x & 63;
    int d = blockIdx.x*4 + w;
    if (d >= NDST) return;
    int off = row_off[d], end = row_off[d+1];
    int deg = end - off;

    float m = -1e30f;
    for (int i = lane; i < deg; i += 64)
        m = fmaxf(m, logits[perm[off+i]]);
#pragma unroll
    for (int s = 32; s >= 1; s >>= 1)
        m = fmaxf(m, __shfl_xor(m, s, 64));

    float ssum = 0.f, acc = 0.f;
    for (int base = 0; base < deg; base += 64) {
        int i = base + lane;
        float p = 0.f; int sj = 0;
        if (i < deg) {
            int e = perm[off+i];
            p  = __expf(logits[e] - m);
            sj = src_idx[e];
        }
        ssum += p;
        psh[w][lane] = p;
        ssh[w][lane] = sj;
        __builtin_amdgcn_wave_barrier();
        int n = (deg - base < 64) ? (deg - base) : 64;
        for (int j = 0; j < n; j++) {
            float pj = psh[w][j];
            int   s2 = ssh[w][j];
            acc += pj * fs[(size_t)s2*DD + lane];
        }
        __builtin_amdgcn_wave_barrier();
    }
#pragma unroll
    for (int s = 32; s >= 1; s >>= 1)
        ssum += __shfl_xor(ssum, s, 64);

    out[(size_t)d*DD + lane] = (deg > 0) ? (acc / ssum) : 0.f;
}

// ---------------- launch ----------------
extern "C" void kernel_launch(void* const* d_in, const int* in_sizes, int n_in,
                              void* d_out, int out_size, void* d_ws, size_t ws_size,
                              hipStream_t stream)
{
    const float* feat_src = (const float*)d_in[0];
    const float* feat_dst = (const float*)d_in[1];
    const float* e_feat   = (const float*)d_in[2];
    const float* W_src = (const float*)d_in[3];
    const float* b_src = (const float*)d_in[4];
    const float* W_dst = (const float*)d_in[5];
    const float* b_dst = (const float*)d_in[6];
    const float* W_e   = (const float*)d_in[7];
    const float* b_e   = (const float*)d_in[8];
    const float* W_m1  = (const float*)d_in[9];
    const float* b_m1  = (const float*)d_in[10];
    const float* W_m2  = (const float*)d_in[11];
    const float* b_m2  = (const float*)d_in[12];
    const float* W_m3  = (const float*)d_in[13];
    const float* b_m3  = (const float*)d_in[14];
    const float* W_el  = (const float*)d_in[15];
    const float* b_el  = (const float*)d_in[16];
    const float* attn  = (const float*)d_in[17];
    const int* src_idx = (const int*)d_in[18];
    const int* dst_idx = (const int*)d_in[19];
    float* out = (float*)d_out;

    char* ws = (char*)d_ws;
    float* fs      = (float*)(ws + OFF_FS);
    float* fd      = (float*)(ws + OFF_FD);
    float* logits  = (float*)(ws + OFF_LOGITS);
    float* wla     = (float*)(ws + OFF_WLA);
    int*   cnt     = (int*)  (ws + OFF_CNT);
    int*   cur     = (int*)  (ws + OFF_CUR);
    int*   row_off = (int*)  (ws + OFF_ROWOFF);
    int*   bsum    = (int*)  (ws + OFF_BSUM);
    int*   bbase   = (int*)  (ws + OFF_BBASE);
    int*   perm    = (int*)  (ws + OFF_PERM);
    ushort_t* wt   = (ushort_t*)(ws + OFF_WT);

    const int NB_E256 = (NE + 255) / 256;            // 6250
    const int NB_SCAN = (NDST + 1023) / 1024;        // 49
    const int NB_PREP = 7 + (NDST + 255) / 256;      // 7 + 196

    k_prep<<<NB_PREP, 256, 0, stream>>>(W_e, W_m1, W_m2, W_m3, W_src, W_dst,
                                        W_el, b_el, attn, wt, wla, cnt);
    k_nodeproj<<<1564, 256, 0, stream>>>(feat_src, feat_dst, b_src, b_dst, wt, fs, fd);
    k_hist<<<NB_E256, 256, 0, stream>>>(dst_idx, cnt);
    k_scan_a<<<NB_SCAN, 1024, 0, stream>>>(cnt, row_off, bsum);
    k_scan_b<<<1, 64, 0, stream>>>(bsum, bbase, row_off, NB_SCAN);
    k_scan_c<<<NB_SCAN, 1024, 0, stream>>>(cnt, bbase, row_off, cur);
    k_scatter<<<NB_E256, 256, 0, stream>>>(dst_idx, cur, perm);
    k_edge<<<NE/64, 256, 0, stream>>>(e_feat, wt, b_e, b_m1, b_m2, b_m3,
                                      src_idx, dst_idx, fs, fd, wla, logits);
    k_agg<<<(NDST + 3) / 4, 256, 0, stream>>>(row_off, perm, logits, src_idx, fs, out);
}